// Round 5
// baseline (773.713 us; speedup 1.0000x reference)
//
#include <hip/hip_runtime.h>
#include <hip/hip_bf16.h>

#define DF 128
#define BSH 5                 // bucket = dst >> 5  (32 nodes / bucket)
#define BNODES 32
#define NBMAX 2048            // max buckets supported (50000/32 = 1563)
#define CHUNK 8192            // edges per hist/bin block

typedef __attribute__((ext_vector_type(8))) short short8;
typedef __attribute__((ext_vector_type(4))) float floatx4;

__device__ __forceinline__ ushort f2bf(float f) {
    __hip_bfloat16 h = __float2bfloat16(f);   // RNE
    return *reinterpret_cast<ushort*>(&h);
}

// ---------------------------------------------------------------------------
// x (fp32) -> xbf (bf16), 4 elements/thread
// ---------------------------------------------------------------------------
__global__ __launch_bounds__(256) void convert_x_kernel(
    const float* __restrict__ x, ushort* __restrict__ xbf, int n4)
{
    int i = blockIdx.x * 256 + threadIdx.x;
    if (i >= n4) return;
    float4 v = reinterpret_cast<const float4*>(x)[i];
    ushort4 o;
    o.x = f2bf(v.x); o.y = f2bf(v.y); o.z = f2bf(v.z); o.w = f2bf(v.w);
    reinterpret_cast<ushort4*>(xbf)[i] = o;
}

__global__ __launch_bounds__(256) void convert_w_kernel(
    const float* __restrict__ W1, const float* __restrict__ W2,
    const float* __restrict__ b1, const float* __restrict__ b2,
    ushort* __restrict__ w1bf, ushort* __restrict__ w2bf,
    float* __restrict__ bias)
{
    int i = blockIdx.x * 256 + threadIdx.x;
    if (i < DF * DF) {
        w1bf[i] = f2bf(W1[i]);
        w2bf[i] = f2bf(W2[i]);
    }
    if (i < DF) bias[i] = b1[i] + b2[i];
}

// ---------------------------------------------------------------------------
// Phase 1: per-(bucket,block) histogram. LDS atomics only, no global atomics.
// histG layout: [bucket][block]  (bucket-major so a flat exclusive scan gives
// final write positions directly).
// ---------------------------------------------------------------------------
__global__ __launch_bounds__(256) void hist_kernel(
    const int* __restrict__ dst, int* __restrict__ histG,
    int n_edges, int B_, int nb)
{
    __shared__ int h[NBMAX];
    for (int j = threadIdx.x; j < nb; j += 256) h[j] = 0;
    __syncthreads();
    int base = blockIdx.x * CHUNK;
#pragma unroll 4
    for (int i = 0; i < CHUNK / 256; ++i) {
        int e = base + i * 256 + threadIdx.x;
        if (e < n_edges) atomicAdd(&h[dst[e] >> BSH], 1);
    }
    __syncthreads();
    for (int j = threadIdx.x; j < nb; j += 256)
        histG[j * B_ + blockIdx.x] = h[j];
}

// ---------------------------------------------------------------------------
// Hierarchical exclusive scan over the flat [nb*B] matrix (3 phases).
// ---------------------------------------------------------------------------
__global__ __launch_bounds__(256) void scan_local_kernel(
    const int* __restrict__ cnt, int* __restrict__ offs,
    int* __restrict__ bsum, int n)
{
    __shared__ int sd[256];
    int t = threadIdx.x;
    int base = blockIdx.x * 1024 + t * 4;

    int4 v = make_int4(0, 0, 0, 0);
    if (base + 3 < n) {
        v = *reinterpret_cast<const int4*>(cnt + base);
    } else {
        if (base + 0 < n) v.x = cnt[base + 0];
        if (base + 1 < n) v.y = cnt[base + 1];
        if (base + 2 < n) v.z = cnt[base + 2];
        if (base + 3 < n) v.w = cnt[base + 3];
    }
    int s = v.x + v.y + v.z + v.w;
    sd[t] = s;
    __syncthreads();
    for (int off = 1; off < 256; off <<= 1) {
        int u = (t >= off) ? sd[t - off] : 0;
        __syncthreads();
        sd[t] += u;
        __syncthreads();
    }
    int incl = sd[t];
    int excl = incl - s;
    if (t == 255) bsum[blockIdx.x] = incl;

    int p0 = excl, p1 = p0 + v.x, p2 = p1 + v.y, p3 = p2 + v.z;
    if (base + 0 < n) offs[base + 0] = p0;
    if (base + 1 < n) offs[base + 1] = p1;
    if (base + 2 < n) offs[base + 2] = p2;
    if (base + 3 < n) offs[base + 3] = p3;
}

__global__ __launch_bounds__(1024) void scan_bsum_kernel(
    int* __restrict__ bsum, int* __restrict__ offs, int nb2, int n)
{
    __shared__ int sd[1024];
    int t = threadIdx.x;
    int v = (t < nb2) ? bsum[t] : 0;
    sd[t] = v;
    __syncthreads();
    for (int off = 1; off < 1024; off <<= 1) {
        int u = (t >= off) ? sd[t - off] : 0;
        __syncthreads();
        sd[t] += u;
        __syncthreads();
    }
    if (t < nb2) bsum[t] = sd[t] - v;
    if (t == 1023) offs[n] = sd[1023];
}

__global__ __launch_bounds__(256) void add_base_kernel(
    int* __restrict__ offs, const int* __restrict__ bsum, int n)
{
    int bb = bsum[blockIdx.x];
    int base = blockIdx.x * 1024 + threadIdx.x * 4;
#pragma unroll
    for (int i = 0; i < 4; ++i) {
        int idx = base + i;
        if (idx < n) offs[idx] += bb;
    }
}

// ---------------------------------------------------------------------------
// Phase 2: bin edges. Each block copies its scanned cursor column into LDS,
// then writes packed (src | dstLocal<<27) to exact positions. No global
// atomics; positions within a (bucket,block) cell via LDS atomic cursor.
// ---------------------------------------------------------------------------
__global__ __launch_bounds__(256) void bin_kernel(
    const int* __restrict__ src, const int* __restrict__ dst,
    const int* __restrict__ histS, uint* __restrict__ pairs,
    int n_edges, int B_, int nb)
{
    __shared__ int cur[NBMAX];
    int blk = blockIdx.x;
    for (int j = threadIdx.x; j < nb; j += 256)
        cur[j] = histS[j * B_ + blk];
    __syncthreads();
    int base = blk * CHUNK;
#pragma unroll 4
    for (int i = 0; i < CHUNK / 256; ++i) {
        int e = base + i * 256 + threadIdx.x;
        if (e < n_edges) {
            int d = dst[e];
            int j = d >> BSH;
            int p = atomicAdd(&cur[j], 1);
            pairs[p] = (uint)src[e] | ((uint)(d & (BNODES - 1)) << 27);
        }
    }
}

// ---------------------------------------------------------------------------
// Phase 3: bucket aggregation. One block per bucket (32 nodes). Edges for the
// bucket are contiguous in pairs[]. Accumulate fp32 in LDS (ds_add_f32),
// 64 lanes = one full x-row per edge. Emit bf16 aggr.
// ---------------------------------------------------------------------------
__global__ __launch_bounds__(256) void aggregate3_kernel(
    const ushort* __restrict__ xbf, const uint* __restrict__ pairs,
    const int* __restrict__ histS, ushort* __restrict__ abf,
    int n_nodes, int n_edges, int B_, int nb)
{
    __shared__ float acc[BNODES * DF];   // 16 KB
    int b = blockIdx.x;
    for (int i = threadIdx.x; i < BNODES * DF; i += 256) acc[i] = 0.f;

    int e0 = histS[b * B_];
    int e1 = (b + 1 < nb) ? histS[(b + 1) * B_] : n_edges;
    __syncthreads();

    int wave = threadIdx.x >> 6;
    int lane = threadIdx.x & 63;
    const uint* xv = reinterpret_cast<const uint*>(xbf);

    int e = e0 + wave;
    for (; e + 4 < e1; e += 8) {          // this wave: e and e+4 (waves stride 4)
        uint pk0 = pairs[e];
        uint pk1 = pairs[e + 4];
        int  s0  = pk0 & 0x07ffffff, d0 = pk0 >> 27;
        int  s1  = pk1 & 0x07ffffff, d1 = pk1 >> 27;
        uint u0 = xv[(size_t)s0 * 64 + lane];
        uint u1 = xv[(size_t)s1 * 64 + lane];
        atomicAdd(&acc[d0 * DF + 2 * lane],     __uint_as_float(u0 << 16));
        atomicAdd(&acc[d0 * DF + 2 * lane + 1], __uint_as_float(u0 & 0xffff0000u));
        atomicAdd(&acc[d1 * DF + 2 * lane],     __uint_as_float(u1 << 16));
        atomicAdd(&acc[d1 * DF + 2 * lane + 1], __uint_as_float(u1 & 0xffff0000u));
    }
    for (; e < e1; e += 4) {
        uint pk = pairs[e];
        int  s  = pk & 0x07ffffff, d = pk >> 27;
        uint u = xv[(size_t)s * 64 + lane];
        atomicAdd(&acc[d * DF + 2 * lane],     __uint_as_float(u << 16));
        atomicAdd(&acc[d * DF + 2 * lane + 1], __uint_as_float(u & 0xffff0000u));
    }
    __syncthreads();

    int node0 = b * BNODES;
    for (int i = threadIdx.x; i < BNODES * 64; i += 256) {
        int nl = i >> 6;          // local node
        int c  = i & 63;          // uint column (2 bf16)
        int node = node0 + nl;
        if (node < n_nodes) {
            float a0 = acc[nl * DF + 2 * c];
            float a1 = acc[nl * DF + 2 * c + 1];
            reinterpret_cast<uint*>(abf)[(size_t)node * 64 + c] =
                (uint)f2bf(a0) | ((uint)f2bf(a1) << 16);
        }
    }
}

// ---------------------------------------------------------------------------
// Fused MFMA GEMM: out[n,o] = x@W1^T + aggr@W2^T + (b1+b2)
// ---------------------------------------------------------------------------
__global__ __launch_bounds__(256) void mfma_gemm_kernel(
    const ushort* __restrict__ xbf, const ushort* __restrict__ abf,
    const ushort* __restrict__ w1, const ushort* __restrict__ w2,
    const float* __restrict__ bias, float* __restrict__ out, int n_nodes)
{
    int wave = threadIdx.x >> 6;
    int lane = threadIdx.x & 63;
    int n0 = blockIdx.x * 64 + wave * 16;
    if (n0 >= n_nodes) return;

    int quad = lane >> 4;
    int m    = lane & 15;

    int arow = n0 + m;
    if (arow >= n_nodes) arow = n_nodes - 1;   // clamp loads; stores guarded

    short8 xa[4], aa[4];
#pragma unroll
    for (int ks = 0; ks < 4; ++ks) {
        xa[ks] = *reinterpret_cast<const short8*>(xbf + (size_t)arow * DF + ks * 32 + quad * 8);
        aa[ks] = *reinterpret_cast<const short8*>(abf + (size_t)arow * DF + ks * 32 + quad * 8);
    }

#pragma unroll
    for (int ot = 0; ot < 8; ++ot) {
        int o = ot * 16 + m;
        floatx4 c = {0.f, 0.f, 0.f, 0.f};
#pragma unroll
        for (int ks = 0; ks < 4; ++ks) {
            short8 bf1 = *reinterpret_cast<const short8*>(w1 + (size_t)o * DF + ks * 32 + quad * 8);
            short8 bf2 = *reinterpret_cast<const short8*>(w2 + (size_t)o * DF + ks * 32 + quad * 8);
            c = __builtin_amdgcn_mfma_f32_16x16x32_bf16(xa[ks], bf1, c, 0, 0, 0);
            c = __builtin_amdgcn_mfma_f32_16x16x32_bf16(aa[ks], bf2, c, 0, 0, 0);
        }
        float bv = bias[o];
#pragma unroll
        for (int r = 0; r < 4; ++r) {
            int row = n0 + quad * 4 + r;
            if (row < n_nodes) out[(size_t)row * DF + o] = c[r] + bv;
        }
    }
}

extern "C" void kernel_launch(void* const* d_in, const int* in_sizes, int n_in,
                              void* d_out, int out_size, void* d_ws, size_t ws_size,
                              hipStream_t stream) {
    const float* x  = (const float*)d_in[0];
    const float* W1 = (const float*)d_in[1];
    const float* b1 = (const float*)d_in[2];
    const float* W2 = (const float*)d_in[3];
    const float* b2 = (const float*)d_in[4];
    const int* esrc = (const int*)d_in[5];
    const int* edst = (const int*)d_in[6];
    float* out = (float*)d_out;

    int n_nodes = in_sizes[0] / DF;
    int n_edges = in_sizes[5];

    int nb = (n_nodes + BNODES - 1) >> BSH;       // buckets (1563)
    int B_ = (n_edges + CHUNK - 1) / CHUNK;       // edge chunks (98)
    int flat = nb * B_;                           // hist matrix size (153k)

    // Workspace layout:
    //   xbf   : n_nodes*DF bf16       (12.8 MB)
    //   abf   : n_nodes*DF bf16       (12.8 MB)
    //   w1bf, w2bf : DF*DF bf16 each  (32 KB x2)
    //   bias  : DF fp32
    //   histG : flat int              (~613 KB)
    //   histS : flat+1 int            (~613 KB)
    //   bsum  : 1024 int
    //   pairs : n_edges uint          (3.2 MB)
    char* ws = (char*)d_ws;
    ushort* xbf   = (ushort*)ws;                 ws += (size_t)n_nodes * DF * 2;
    ushort* abf   = (ushort*)ws;                 ws += (size_t)n_nodes * DF * 2;
    ushort* w1bf  = (ushort*)ws;                 ws += (size_t)DF * DF * 2;
    ushort* w2bf  = (ushort*)ws;                 ws += (size_t)DF * DF * 2;
    float*  bias  = (float*)ws;                  ws += (size_t)DF * 4;
    int*    histG = (int*)ws;                    ws += (size_t)flat * 4;
    int*    histS = (int*)ws;                    ws += (size_t)(flat + 1) * 4;
    int*    bsum  = (int*)ws;                    ws += 1024 * 4;
    uint*   pairs = (uint*)ws;

    int n4 = n_nodes * DF / 4;
    convert_x_kernel<<<(n4 + 255) / 256, 256, 0, stream>>>(x, xbf, n4);
    convert_w_kernel<<<(DF * DF + 255) / 256, 256, 0, stream>>>(W1, W2, b1, b2, w1bf, w2bf, bias);

    hist_kernel<<<B_, 256, 0, stream>>>(edst, histG, n_edges, B_, nb);

    int nb2 = (flat + 1023) / 1024;               // scan blocks (150)
    scan_local_kernel<<<nb2, 256, 0, stream>>>(histG, histS, bsum, flat);
    scan_bsum_kernel<<<1, 1024, 0, stream>>>(bsum, histS, nb2, flat);
    add_base_kernel<<<nb2, 256, 0, stream>>>(histS, bsum, flat);

    bin_kernel<<<B_, 256, 0, stream>>>(esrc, edst, histS, pairs, n_edges, B_, nb);

    aggregate3_kernel<<<nb, 256, 0, stream>>>(xbf, pairs, histS, abf,
                                              n_nodes, n_edges, B_, nb);

    mfma_gemm_kernel<<<(n_nodes + 63) / 64, 256, 0, stream>>>(xbf, abf, w1bf, w2bf, bias, out, n_nodes);
}

// Round 6
// 214.137 us; speedup vs baseline: 3.6132x; 3.6132x over previous
//
#include <hip/hip_runtime.h>
#include <hip/hip_bf16.h>

#define DF 128
#define BSH 5                 // bucket = dst >> 5  (32 nodes / bucket)
#define BNODES 32
#define NBMAX 2048            // max buckets supported (50000/32 = 1563)
#define CHUNK 8192            // edges per hist/bin block
#define TILE 4096             // edges per aggregation LDS tile

typedef __attribute__((ext_vector_type(8))) short short8;
typedef __attribute__((ext_vector_type(4))) float floatx4;

__device__ __forceinline__ ushort f2bf(float f) {
    __hip_bfloat16 h = __float2bfloat16(f);   // RNE
    return *reinterpret_cast<ushort*>(&h);
}

// ---------------------------------------------------------------------------
// x (fp32) -> xbf (bf16), 4 elements/thread
// ---------------------------------------------------------------------------
__global__ __launch_bounds__(256) void convert_x_kernel(
    const float* __restrict__ x, ushort* __restrict__ xbf, int n4)
{
    int i = blockIdx.x * 256 + threadIdx.x;
    if (i >= n4) return;
    float4 v = reinterpret_cast<const float4*>(x)[i];
    ushort4 o;
    o.x = f2bf(v.x); o.y = f2bf(v.y); o.z = f2bf(v.z); o.w = f2bf(v.w);
    reinterpret_cast<ushort4*>(xbf)[i] = o;
}

__global__ __launch_bounds__(256) void convert_w_kernel(
    const float* __restrict__ W1, const float* __restrict__ W2,
    const float* __restrict__ b1, const float* __restrict__ b2,
    ushort* __restrict__ w1bf, ushort* __restrict__ w2bf,
    float* __restrict__ bias)
{
    int i = blockIdx.x * 256 + threadIdx.x;
    if (i < DF * DF) {
        w1bf[i] = f2bf(W1[i]);
        w2bf[i] = f2bf(W2[i]);
    }
    if (i < DF) bias[i] = b1[i] + b2[i];
}

// ---------------------------------------------------------------------------
// Phase 1: per-(bucket,block) histogram. LDS int atomics only.
// histG layout: [bucket][block] (bucket-major: flat scan = write positions).
// ---------------------------------------------------------------------------
__global__ __launch_bounds__(256) void hist_kernel(
    const int* __restrict__ dst, int* __restrict__ histG,
    int n_edges, int B_, int nb)
{
    __shared__ int h[NBMAX];
    for (int j = threadIdx.x; j < nb; j += 256) h[j] = 0;
    __syncthreads();
    int base = blockIdx.x * CHUNK;
#pragma unroll 4
    for (int i = 0; i < CHUNK / 256; ++i) {
        int e = base + i * 256 + threadIdx.x;
        if (e < n_edges) atomicAdd(&h[dst[e] >> BSH], 1);
    }
    __syncthreads();
    for (int j = threadIdx.x; j < nb; j += 256)
        histG[j * B_ + blockIdx.x] = h[j];
}

// ---------------------------------------------------------------------------
// Hierarchical exclusive scan over the flat [nb*B] matrix (3 phases).
// ---------------------------------------------------------------------------
__global__ __launch_bounds__(256) void scan_local_kernel(
    const int* __restrict__ cnt, int* __restrict__ offs,
    int* __restrict__ bsum, int n)
{
    __shared__ int sd[256];
    int t = threadIdx.x;
    int base = blockIdx.x * 1024 + t * 4;

    int4 v = make_int4(0, 0, 0, 0);
    if (base + 3 < n) {
        v = *reinterpret_cast<const int4*>(cnt + base);
    } else {
        if (base + 0 < n) v.x = cnt[base + 0];
        if (base + 1 < n) v.y = cnt[base + 1];
        if (base + 2 < n) v.z = cnt[base + 2];
        if (base + 3 < n) v.w = cnt[base + 3];
    }
    int s = v.x + v.y + v.z + v.w;
    sd[t] = s;
    __syncthreads();
    for (int off = 1; off < 256; off <<= 1) {
        int u = (t >= off) ? sd[t - off] : 0;
        __syncthreads();
        sd[t] += u;
        __syncthreads();
    }
    int incl = sd[t];
    int excl = incl - s;
    if (t == 255) bsum[blockIdx.x] = incl;

    int p0 = excl, p1 = p0 + v.x, p2 = p1 + v.y, p3 = p2 + v.z;
    if (base + 0 < n) offs[base + 0] = p0;
    if (base + 1 < n) offs[base + 1] = p1;
    if (base + 2 < n) offs[base + 2] = p2;
    if (base + 3 < n) offs[base + 3] = p3;
}

__global__ __launch_bounds__(1024) void scan_bsum_kernel(
    int* __restrict__ bsum, int* __restrict__ offs, int nb2, int n)
{
    __shared__ int sd[1024];
    int t = threadIdx.x;
    int v = (t < nb2) ? bsum[t] : 0;
    sd[t] = v;
    __syncthreads();
    for (int off = 1; off < 1024; off <<= 1) {
        int u = (t >= off) ? sd[t - off] : 0;
        __syncthreads();
        sd[t] += u;
        __syncthreads();
    }
    if (t < nb2) bsum[t] = sd[t] - v;
    if (t == 1023) offs[n] = sd[1023];
}

__global__ __launch_bounds__(256) void add_base_kernel(
    int* __restrict__ offs, const int* __restrict__ bsum, int n)
{
    int bb = bsum[blockIdx.x];
    int base = blockIdx.x * 1024 + threadIdx.x * 4;
#pragma unroll
    for (int i = 0; i < 4; ++i) {
        int idx = base + i;
        if (idx < n) offs[idx] += bb;
    }
}

// ---------------------------------------------------------------------------
// Phase 2: bin edges to bucket-contiguous packed array.
// pairs[p] = src | dstLocal<<27. LDS int cursors, no global atomics.
// ---------------------------------------------------------------------------
__global__ __launch_bounds__(256) void bin_kernel(
    const int* __restrict__ src, const int* __restrict__ dst,
    const int* __restrict__ histS, uint* __restrict__ pairs,
    int n_edges, int B_, int nb)
{
    __shared__ int cur[NBMAX];
    int blk = blockIdx.x;
    for (int j = threadIdx.x; j < nb; j += 256)
        cur[j] = histS[j * B_ + blk];
    __syncthreads();
    int base = blk * CHUNK;
#pragma unroll 4
    for (int i = 0; i < CHUNK / 256; ++i) {
        int e = base + i * 256 + threadIdx.x;
        if (e < n_edges) {
            int d = dst[e];
            int j = d >> BSH;
            int p = atomicAdd(&cur[j], 1);
            pairs[p] = (uint)src[e] | ((uint)(d & (BNODES - 1)) << 27);
        }
    }
}

// ---------------------------------------------------------------------------
// Phase 3: bucket aggregation, NO fp atomics. One block per bucket.
// Tile of bucket edges -> LDS; int-atomic node histogram + shfl scan ->
// node-sorted src list in LDS; each wave owns 8 nodes and register-
// accumulates float2/lane with 4-wide independent gathers. bf16 out.
// ---------------------------------------------------------------------------
__global__ __launch_bounds__(256) void aggregate4_kernel(
    const ushort* __restrict__ xbf, const uint* __restrict__ pairs,
    const int* __restrict__ histS, ushort* __restrict__ abf,
    int n_nodes, int n_edges, int B_, int nb)
{
    __shared__ uint raw[TILE];       // 16 KB
    __shared__ uint sorted[TILE];    // 16 KB
    __shared__ int hcnt[BNODES];
    __shared__ int hoff[BNODES + 1];
    __shared__ int hcur[BNODES];

    int b = blockIdx.x;
    int wave = threadIdx.x >> 6;
    int lane = threadIdx.x & 63;

    int e0 = histS[b * B_];
    int e1 = (b + 1 < nb) ? histS[(b + 1) * B_] : n_edges;

    const uint* xv = reinterpret_cast<const uint*>(xbf);
    float2 acc[8];
#pragma unroll
    for (int i = 0; i < 8; ++i) acc[i] = make_float2(0.f, 0.f);

    for (int t0 = e0; t0 < e1; t0 += TILE) {
        int cnt = e1 - t0; if (cnt > TILE) cnt = TILE;

        if (threadIdx.x < BNODES) hcnt[threadIdx.x] = 0;
        __syncthreads();

        for (int i = threadIdx.x; i < cnt; i += 256) {
            uint pk = pairs[t0 + i];
            raw[i] = pk;
            atomicAdd(&hcnt[pk >> 27], 1);
        }
        __syncthreads();

        // 32-entry exclusive scan by wave 0 via shfl
        if (threadIdx.x < 64) {
            int v = (lane < BNODES) ? hcnt[lane] : 0;
#pragma unroll
            for (int off = 1; off < BNODES; off <<= 1) {
                int u = __shfl_up(v, off);
                if (lane >= off) v += u;
            }
            if (lane < BNODES) {
                hoff[lane + 1] = v;
                hcur[lane] = v - hcnt[lane];
            }
            if (lane == 0) hoff[0] = 0;
        }
        __syncthreads();

        // scatter srcs into node-sorted order (int LDS atomics, native)
        for (int i = threadIdx.x; i < cnt; i += 256) {
            uint pk = raw[i];
            int d = pk >> 27;
            int p = atomicAdd(&hcur[d], 1);
            sorted[p] = pk & 0x07ffffffu;
        }
        __syncthreads();

        // wave w accumulates nodes w*8 .. w*8+7
#pragma unroll
        for (int i = 0; i < 8; ++i) {
            int nl = wave * 8 + i;
            int j0 = hoff[nl], j1 = hoff[nl + 1];
            float2 a = acc[i];
            int j = j0;
            for (; j + 3 < j1; j += 4) {
                uint s0 = sorted[j], s1 = sorted[j + 1];
                uint s2 = sorted[j + 2], s3 = sorted[j + 3];
                uint u0 = xv[(size_t)s0 * 64 + lane];
                uint u1 = xv[(size_t)s1 * 64 + lane];
                uint u2 = xv[(size_t)s2 * 64 + lane];
                uint u3 = xv[(size_t)s3 * 64 + lane];
                a.x += __uint_as_float(u0 << 16) + __uint_as_float(u1 << 16)
                     + __uint_as_float(u2 << 16) + __uint_as_float(u3 << 16);
                a.y += __uint_as_float(u0 & 0xffff0000u) + __uint_as_float(u1 & 0xffff0000u)
                     + __uint_as_float(u2 & 0xffff0000u) + __uint_as_float(u3 & 0xffff0000u);
            }
            for (; j < j1; ++j) {
                uint u = xv[(size_t)sorted[j] * 64 + lane];
                a.x += __uint_as_float(u << 16);
                a.y += __uint_as_float(u & 0xffff0000u);
            }
            acc[i] = a;
        }
        __syncthreads();   // protect raw/sorted/hist before next tile
    }

    int node0 = b * BNODES + wave * 8;
#pragma unroll
    for (int i = 0; i < 8; ++i) {
        int node = node0 + i;
        if (node < n_nodes) {
            uint packed = (uint)f2bf(acc[i].x) | ((uint)f2bf(acc[i].y) << 16);
            reinterpret_cast<uint*>(abf)[(size_t)node * 64 + lane] = packed;
        }
    }
}

// ---------------------------------------------------------------------------
// Fused MFMA GEMM: out[n,o] = x@W1^T + aggr@W2^T + (b1+b2)
// ---------------------------------------------------------------------------
__global__ __launch_bounds__(256) void mfma_gemm_kernel(
    const ushort* __restrict__ xbf, const ushort* __restrict__ abf,
    const ushort* __restrict__ w1, const ushort* __restrict__ w2,
    const float* __restrict__ bias, float* __restrict__ out, int n_nodes)
{
    int wave = threadIdx.x >> 6;
    int lane = threadIdx.x & 63;
    int n0 = blockIdx.x * 64 + wave * 16;
    if (n0 >= n_nodes) return;

    int quad = lane >> 4;
    int m    = lane & 15;

    int arow = n0 + m;
    if (arow >= n_nodes) arow = n_nodes - 1;   // clamp loads; stores guarded

    short8 xa[4], aa[4];
#pragma unroll
    for (int ks = 0; ks < 4; ++ks) {
        xa[ks] = *reinterpret_cast<const short8*>(xbf + (size_t)arow * DF + ks * 32 + quad * 8);
        aa[ks] = *reinterpret_cast<const short8*>(abf + (size_t)arow * DF + ks * 32 + quad * 8);
    }

#pragma unroll
    for (int ot = 0; ot < 8; ++ot) {
        int o = ot * 16 + m;
        floatx4 c = {0.f, 0.f, 0.f, 0.f};
#pragma unroll
        for (int ks = 0; ks < 4; ++ks) {
            short8 bf1 = *reinterpret_cast<const short8*>(w1 + (size_t)o * DF + ks * 32 + quad * 8);
            short8 bf2 = *reinterpret_cast<const short8*>(w2 + (size_t)o * DF + ks * 32 + quad * 8);
            c = __builtin_amdgcn_mfma_f32_16x16x32_bf16(xa[ks], bf1, c, 0, 0, 0);
            c = __builtin_amdgcn_mfma_f32_16x16x32_bf16(aa[ks], bf2, c, 0, 0, 0);
        }
        float bv = bias[o];
#pragma unroll
        for (int r = 0; r < 4; ++r) {
            int row = n0 + quad * 4 + r;
            if (row < n_nodes) out[(size_t)row * DF + o] = c[r] + bv;
        }
    }
}

extern "C" void kernel_launch(void* const* d_in, const int* in_sizes, int n_in,
                              void* d_out, int out_size, void* d_ws, size_t ws_size,
                              hipStream_t stream) {
    const float* x  = (const float*)d_in[0];
    const float* W1 = (const float*)d_in[1];
    const float* b1 = (const float*)d_in[2];
    const float* W2 = (const float*)d_in[3];
    const float* b2 = (const float*)d_in[4];
    const int* esrc = (const int*)d_in[5];
    const int* edst = (const int*)d_in[6];
    float* out = (float*)d_out;

    int n_nodes = in_sizes[0] / DF;
    int n_edges = in_sizes[5];

    int nb = (n_nodes + BNODES - 1) >> BSH;       // buckets (1563)
    int B_ = (n_edges + CHUNK - 1) / CHUNK;       // edge chunks (98)
    int flat = nb * B_;                           // hist matrix size (~153k)

    char* ws = (char*)d_ws;
    ushort* xbf   = (ushort*)ws;                 ws += (size_t)n_nodes * DF * 2;
    ushort* abf   = (ushort*)ws;                 ws += (size_t)n_nodes * DF * 2;
    ushort* w1bf  = (ushort*)ws;                 ws += (size_t)DF * DF * 2;
    ushort* w2bf  = (ushort*)ws;                 ws += (size_t)DF * DF * 2;
    float*  bias  = (float*)ws;                  ws += (size_t)DF * 4;
    int*    histG = (int*)ws;                    ws += (size_t)flat * 4;
    int*    histS = (int*)ws;                    ws += (size_t)(flat + 1) * 4;
    int*    bsum  = (int*)ws;                    ws += 1024 * 4;
    uint*   pairs = (uint*)ws;

    int n4 = n_nodes * DF / 4;
    convert_x_kernel<<<(n4 + 255) / 256, 256, 0, stream>>>(x, xbf, n4);
    convert_w_kernel<<<(DF * DF + 255) / 256, 256, 0, stream>>>(W1, W2, b1, b2, w1bf, w2bf, bias);

    hist_kernel<<<B_, 256, 0, stream>>>(edst, histG, n_edges, B_, nb);

    int nb2 = (flat + 1023) / 1024;
    scan_local_kernel<<<nb2, 256, 0, stream>>>(histG, histS, bsum, flat);
    scan_bsum_kernel<<<1, 1024, 0, stream>>>(bsum, histS, nb2, flat);
    add_base_kernel<<<nb2, 256, 0, stream>>>(histS, bsum, flat);

    bin_kernel<<<B_, 256, 0, stream>>>(esrc, edst, histS, pairs, n_edges, B_, nb);

    aggregate4_kernel<<<nb, 256, 0, stream>>>(xbf, pairs, histS, abf,
                                              n_nodes, n_edges, B_, nb);

    mfma_gemm_kernel<<<(n_nodes + 63) / 64, 256, 0, stream>>>(xbf, abf, w1bf, w2bf, bias, out, n_nodes);
}

// Round 7
// 197.933 us; speedup vs baseline: 3.9090x; 1.0819x over previous
//
#include <hip/hip_runtime.h>
#include <hip/hip_bf16.h>

#define DF 128
#define BSH 5                 // bucket = dst >> 5  (32 nodes / bucket)
#define BNODES 32
#define NBMAX 2048            // max buckets supported (50000/32 = 1563)
#define CHUNK 8192            // edges per hist/bin block
#define TILE 2048             // edges per aggregation LDS tile (bucket-pair ~1024)
#define ASTRIDE 68            // uints per abuf row (64 data + 4 pad: bank spread)

typedef __attribute__((ext_vector_type(8))) short short8;
typedef __attribute__((ext_vector_type(4))) float floatx4;

__device__ __forceinline__ ushort f2bf(float f) {
    __hip_bfloat16 h = __float2bfloat16(f);   // RNE
    return *reinterpret_cast<ushort*>(&h);
}

// ---------------------------------------------------------------------------
// Fused prep: [0,B_) hist blocks | [B_,B_+64) weight convert | rest x convert.
// hist: per-(bucket,block) histogram, LDS int atomics, histG[bucket][block].
// ---------------------------------------------------------------------------
__global__ __launch_bounds__(256) void prep_kernel(
    const float* __restrict__ x, ushort* __restrict__ xbf, int n4,
    const float* __restrict__ W1, const float* __restrict__ W2,
    const float* __restrict__ b1, const float* __restrict__ b2,
    ushort* __restrict__ w1bf, ushort* __restrict__ w2bf, float* __restrict__ bias,
    const int* __restrict__ dst, int* __restrict__ histG,
    int n_edges, int B_, int nb)
{
    __shared__ int h[NBMAX];
    int bid = blockIdx.x;
    if (bid < B_) {
        for (int j = threadIdx.x; j < nb; j += 256) h[j] = 0;
        __syncthreads();
        int base = bid * CHUNK;
#pragma unroll 4
        for (int i = 0; i < CHUNK / 256; ++i) {
            int e = base + i * 256 + threadIdx.x;
            if (e < n_edges) atomicAdd(&h[dst[e] >> BSH], 1);
        }
        __syncthreads();
        for (int j = threadIdx.x; j < nb; j += 256)
            histG[j * B_ + bid] = h[j];
    } else if (bid < B_ + 64) {
        int i = (bid - B_) * 256 + threadIdx.x;
        if (i < DF * DF) {
            w1bf[i] = f2bf(W1[i]);
            w2bf[i] = f2bf(W2[i]);
        }
        if (i < DF) bias[i] = b1[i] + b2[i];
    } else {
        int i = (bid - B_ - 64) * 256 + threadIdx.x;
        if (i < n4) {
            float4 v = reinterpret_cast<const float4*>(x)[i];
            ushort4 o;
            o.x = f2bf(v.x); o.y = f2bf(v.y); o.z = f2bf(v.z); o.w = f2bf(v.w);
            reinterpret_cast<ushort4*>(xbf)[i] = o;
        }
    }
}

// ---------------------------------------------------------------------------
// Hierarchical exclusive scan, phases A/B. (Base-add is folded into the
// consumers: final_offs(idx) = histS[idx] + bsum[idx>>10].)
// ---------------------------------------------------------------------------
__global__ __launch_bounds__(256) void scan_local_kernel(
    const int* __restrict__ cnt, int* __restrict__ offs,
    int* __restrict__ bsum, int n)
{
    __shared__ int sd[256];
    int t = threadIdx.x;
    int base = blockIdx.x * 1024 + t * 4;

    int4 v = make_int4(0, 0, 0, 0);
    if (base + 3 < n) {
        v = *reinterpret_cast<const int4*>(cnt + base);
    } else {
        if (base + 0 < n) v.x = cnt[base + 0];
        if (base + 1 < n) v.y = cnt[base + 1];
        if (base + 2 < n) v.z = cnt[base + 2];
        if (base + 3 < n) v.w = cnt[base + 3];
    }
    int s = v.x + v.y + v.z + v.w;
    sd[t] = s;
    __syncthreads();
    for (int off = 1; off < 256; off <<= 1) {
        int u = (t >= off) ? sd[t - off] : 0;
        __syncthreads();
        sd[t] += u;
        __syncthreads();
    }
    int incl = sd[t];
    int excl = incl - s;
    if (t == 255) bsum[blockIdx.x] = incl;

    int p0 = excl, p1 = p0 + v.x, p2 = p1 + v.y, p3 = p2 + v.z;
    if (base + 0 < n) offs[base + 0] = p0;
    if (base + 1 < n) offs[base + 1] = p1;
    if (base + 2 < n) offs[base + 2] = p2;
    if (base + 3 < n) offs[base + 3] = p3;
}

__global__ __launch_bounds__(1024) void scan_bsum_kernel(
    int* __restrict__ bsum, int nb2)
{
    __shared__ int sd[1024];
    int t = threadIdx.x;
    int v = (t < nb2) ? bsum[t] : 0;
    sd[t] = v;
    __syncthreads();
    for (int off = 1; off < 1024; off <<= 1) {
        int u = (t >= off) ? sd[t - off] : 0;
        __syncthreads();
        sd[t] += u;
        __syncthreads();
    }
    if (t < nb2) bsum[t] = sd[t] - v;   // exclusive base per scan block
}

// ---------------------------------------------------------------------------
// Bin edges to bucket-contiguous packed array. pairs[p] = src | dstLocal<<27.
// ---------------------------------------------------------------------------
__global__ __launch_bounds__(256) void bin_kernel(
    const int* __restrict__ src, const int* __restrict__ dst,
    const int* __restrict__ histS, const int* __restrict__ bsum,
    uint* __restrict__ pairs, int n_edges, int B_, int nb)
{
    __shared__ int cur[NBMAX];
    int blk = blockIdx.x;
    for (int j = threadIdx.x; j < nb; j += 256) {
        int idx = j * B_ + blk;
        cur[j] = histS[idx] + bsum[idx >> 10];
    }
    __syncthreads();
    int base = blk * CHUNK;
#pragma unroll 4
    for (int i = 0; i < CHUNK / 256; ++i) {
        int e = base + i * 256 + threadIdx.x;
        if (e < n_edges) {
            int d = dst[e];
            int j = d >> BSH;
            int p = atomicAdd(&cur[j], 1);
            pairs[p] = (uint)src[e] | ((uint)(d & (BNODES - 1)) << 27);
        }
    }
}

// ---------------------------------------------------------------------------
// Fused aggregate + MFMA GEMM. Block = 64 nodes = 2 adjacent buckets (their
// edges are contiguous in pairs). Phase A: node-sort tile in LDS (int
// atomics), register float2 accumulate (wave owns 16 nodes). Phase B: stage
// bf16 rows in LDS (padded), MFMA epilogue with W from global, write out.
// ---------------------------------------------------------------------------
__global__ __launch_bounds__(256) void agg_gemm_kernel(
    const ushort* __restrict__ xbf, const uint* __restrict__ pairs,
    const int* __restrict__ histS, const int* __restrict__ bsum,
    const ushort* __restrict__ w1, const ushort* __restrict__ w2,
    const float* __restrict__ bias, float* __restrict__ out,
    int n_nodes, int n_edges, int B_, int nb, int flat)
{
    __shared__ uint sorted[TILE];           // 8 KB
    __shared__ uint abuf[64 * ASTRIDE];     // 17.4 KB
    __shared__ int hcnt[64];
    __shared__ int hoff[65];
    __shared__ int hcur[64];

    int blk  = blockIdx.x;
    int node0 = blk * 64;
    int b0   = blk * 2;
    int wave = threadIdx.x >> 6;
    int lane = threadIdx.x & 63;

    auto loadOffs = [&](int idx) -> int {
        if (idx >= flat) return n_edges;
        return histS[idx] + bsum[idx >> 10];
    };

    int e0  = loadOffs(b0 * B_);
    int mid = loadOffs((b0 + 1) * B_);
    int e1  = loadOffs((b0 + 2) * B_);

    const uint* xv = reinterpret_cast<const uint*>(xbf);
    float2 acc[16];
#pragma unroll
    for (int i = 0; i < 16; ++i) acc[i] = make_float2(0.f, 0.f);

    for (int t0 = e0; t0 < e1; t0 += TILE) {
        int cnt = e1 - t0; if (cnt > TILE) cnt = TILE;

        if (threadIdx.x < 64) hcnt[threadIdx.x] = 0;
        __syncthreads();

        for (int i = threadIdx.x; i < cnt; i += 256) {
            uint pk = pairs[t0 + i];
            int nl = ((t0 + i) >= mid ? BNODES : 0) + (int)(pk >> 27);
            atomicAdd(&hcnt[nl], 1);
        }
        __syncthreads();

        if (threadIdx.x < 64) {
            int v = hcnt[lane];
#pragma unroll
            for (int off = 1; off < 64; off <<= 1) {
                int u = __shfl_up(v, off);
                if (lane >= off) v += u;
            }
            hoff[lane + 1] = v;
            hcur[lane] = v - hcnt[lane];
            if (lane == 0) hoff[0] = 0;
        }
        __syncthreads();

        for (int i = threadIdx.x; i < cnt; i += 256) {
            uint pk = pairs[t0 + i];
            int nl = ((t0 + i) >= mid ? BNODES : 0) + (int)(pk >> 27);
            int p = atomicAdd(&hcur[nl], 1);
            sorted[p] = pk & 0x07ffffffu;
        }
        __syncthreads();

        // wave owns nodes wave*16 .. wave*16+15
#pragma unroll
        for (int i = 0; i < 16; ++i) {
            int nl = wave * 16 + i;
            int j0 = hoff[nl], j1 = hoff[nl + 1];
            float2 a = acc[i];
            int j = j0;
            for (; j + 3 < j1; j += 4) {
                uint s0 = sorted[j],     s1 = sorted[j + 1];
                uint s2 = sorted[j + 2], s3 = sorted[j + 3];
                uint u0 = xv[(size_t)s0 * 64 + lane];
                uint u1 = xv[(size_t)s1 * 64 + lane];
                uint u2 = xv[(size_t)s2 * 64 + lane];
                uint u3 = xv[(size_t)s3 * 64 + lane];
                a.x += __uint_as_float(u0 << 16) + __uint_as_float(u1 << 16)
                     + __uint_as_float(u2 << 16) + __uint_as_float(u3 << 16);
                a.y += __uint_as_float(u0 & 0xffff0000u) + __uint_as_float(u1 & 0xffff0000u)
                     + __uint_as_float(u2 & 0xffff0000u) + __uint_as_float(u3 & 0xffff0000u);
            }
            for (; j < j1; ++j) {
                uint u = xv[(size_t)sorted[j] * 64 + lane];
                a.x += __uint_as_float(u << 16);
                a.y += __uint_as_float(u & 0xffff0000u);
            }
            acc[i] = a;
        }
        __syncthreads();   // protect sorted/hist before next tile
    }

    // stage aggregated rows as bf16 into LDS (row stride 68 uints)
#pragma unroll
    for (int i = 0; i < 16; ++i) {
        int nl = wave * 16 + i;
        abuf[nl * ASTRIDE + lane] =
            (uint)f2bf(acc[i].x) | ((uint)f2bf(acc[i].y) << 16);
    }
    __syncthreads();

    // ---- MFMA phase: wave w handles rows node0 + w*16 .. +15 ----
    int quad = lane >> 4;
    int m    = lane & 15;
    int rowL = wave * 16 + m;
    int rowG = node0 + rowL;
    int rowC = (rowG < n_nodes) ? rowG : (n_nodes - 1);   // clamp loads

    short8 xa[4], aa[4];
#pragma unroll
    for (int ks = 0; ks < 4; ++ks) {
        xa[ks] = *reinterpret_cast<const short8*>(xbf + (size_t)rowC * DF + ks * 32 + quad * 8);
        aa[ks] = *reinterpret_cast<const short8*>(&abuf[rowL * ASTRIDE + ks * 16 + quad * 4]);
    }

    int nbase = node0 + wave * 16;
#pragma unroll
    for (int ot = 0; ot < 8; ++ot) {
        int o = ot * 16 + m;
        floatx4 c = {0.f, 0.f, 0.f, 0.f};
#pragma unroll
        for (int ks = 0; ks < 4; ++ks) {
            short8 bf1 = *reinterpret_cast<const short8*>(w1 + (size_t)o * DF + ks * 32 + quad * 8);
            short8 bf2 = *reinterpret_cast<const short8*>(w2 + (size_t)o * DF + ks * 32 + quad * 8);
            c = __builtin_amdgcn_mfma_f32_16x16x32_bf16(xa[ks], bf1, c, 0, 0, 0);
            c = __builtin_amdgcn_mfma_f32_16x16x32_bf16(aa[ks], bf2, c, 0, 0, 0);
        }
        float bv = bias[o];
#pragma unroll
        for (int r = 0; r < 4; ++r) {
            int row = nbase + quad * 4 + r;
            if (row < n_nodes) out[(size_t)row * DF + o] = c[r] + bv;
        }
    }
}

extern "C" void kernel_launch(void* const* d_in, const int* in_sizes, int n_in,
                              void* d_out, int out_size, void* d_ws, size_t ws_size,
                              hipStream_t stream) {
    const float* x  = (const float*)d_in[0];
    const float* W1 = (const float*)d_in[1];
    const float* b1 = (const float*)d_in[2];
    const float* W2 = (const float*)d_in[3];
    const float* b2 = (const float*)d_in[4];
    const int* esrc = (const int*)d_in[5];
    const int* edst = (const int*)d_in[6];
    float* out = (float*)d_out;

    int n_nodes = in_sizes[0] / DF;
    int n_edges = in_sizes[5];

    int nb = (n_nodes + BNODES - 1) >> BSH;       // buckets (1563)
    int B_ = (n_edges + CHUNK - 1) / CHUNK;       // edge chunks (98)
    int flat = nb * B_;                           // hist matrix size (~153k)

    char* ws = (char*)d_ws;
    ushort* xbf   = (ushort*)ws;                 ws += (size_t)n_nodes * DF * 2;
    ushort* w1bf  = (ushort*)ws;                 ws += (size_t)DF * DF * 2;
    ushort* w2bf  = (ushort*)ws;                 ws += (size_t)DF * DF * 2;
    float*  bias  = (float*)ws;                  ws += (size_t)DF * 4;
    int*    histG = (int*)ws;                    ws += (size_t)flat * 4;
    int*    histS = (int*)ws;                    ws += (size_t)(flat + 1) * 4;
    int*    bsum  = (int*)ws;                    ws += 1024 * 4;
    uint*   pairs = (uint*)ws;

    int n4 = n_nodes * DF / 4;
    int prep_blocks = B_ + 64 + (n4 + 255) / 256;
    prep_kernel<<<prep_blocks, 256, 0, stream>>>(
        x, xbf, n4, W1, W2, b1, b2, w1bf, w2bf, bias,
        edst, histG, n_edges, B_, nb);

    int nb2 = (flat + 1023) / 1024;
    scan_local_kernel<<<nb2, 256, 0, stream>>>(histG, histS, bsum, flat);
    scan_bsum_kernel<<<1, 1024, 0, stream>>>(bsum, nb2);

    bin_kernel<<<B_, 256, 0, stream>>>(esrc, edst, histS, bsum, pairs, n_edges, B_, nb);

    agg_gemm_kernel<<<(n_nodes + 63) / 64, 256, 0, stream>>>(
        xbf, pairs, histS, bsum, w1bf, w2bf, bias, out,
        n_nodes, n_edges, B_, nb, flat);
}

// Round 8
// 194.969 us; speedup vs baseline: 3.9684x; 1.0152x over previous
//
#include <hip/hip_runtime.h>
#include <hip/hip_bf16.h>

#define DF 128
#define BSH 5                 // bucket = dst >> 5  (32 nodes / bucket)
#define BNODES 32
#define NBMAX 2048            // max buckets supported (50000/32 = 1563)
#define CHUNK 8192            // edges per hist/bin block
#define TILE 2048             // edges per aggregation LDS tile (bucket-pair ~1024)
#define ASTRIDE 68            // uints per abuf row (64 data + 4 pad: bank spread)

typedef __attribute__((ext_vector_type(8))) short short8;
typedef __attribute__((ext_vector_type(4))) float floatx4;

__device__ __forceinline__ ushort f2bf(float f) {
    __hip_bfloat16 h = __float2bfloat16(f);   // RNE
    return *reinterpret_cast<ushort*>(&h);
}

// ---------------------------------------------------------------------------
// Fused prep: [0,B_) hist blocks | [B_,B_+64) weight convert | rest x convert.
// ---------------------------------------------------------------------------
__global__ __launch_bounds__(256) void prep_kernel(
    const float* __restrict__ x, ushort* __restrict__ xbf, int n4,
    const float* __restrict__ W1, const float* __restrict__ W2,
    const float* __restrict__ b1, const float* __restrict__ b2,
    ushort* __restrict__ w1bf, ushort* __restrict__ w2bf, float* __restrict__ bias,
    const int* __restrict__ dst, int* __restrict__ histG,
    int n_edges, int B_, int nb)
{
    __shared__ int h[NBMAX];
    int bid = blockIdx.x;
    if (bid < B_) {
        for (int j = threadIdx.x; j < nb; j += 256) h[j] = 0;
        __syncthreads();
        int base = bid * CHUNK;
#pragma unroll 4
        for (int i = 0; i < CHUNK / 256; ++i) {
            int e = base + i * 256 + threadIdx.x;
            if (e < n_edges) atomicAdd(&h[dst[e] >> BSH], 1);
        }
        __syncthreads();
        for (int j = threadIdx.x; j < nb; j += 256)
            histG[j * B_ + bid] = h[j];
    } else if (bid < B_ + 64) {
        int i = (bid - B_) * 256 + threadIdx.x;
        if (i < DF * DF) {
            w1bf[i] = f2bf(W1[i]);
            w2bf[i] = f2bf(W2[i]);
        }
        if (i < DF) bias[i] = b1[i] + b2[i];
    } else {
        int i = (bid - B_ - 64) * 256 + threadIdx.x;
        if (i < n4) {
            float4 v = reinterpret_cast<const float4*>(x)[i];
            ushort4 o;
            o.x = f2bf(v.x); o.y = f2bf(v.y); o.z = f2bf(v.z); o.w = f2bf(v.w);
            reinterpret_cast<ushort4*>(xbf)[i] = o;
        }
    }
}

// ---------------------------------------------------------------------------
// Hierarchical exclusive scan, phases A/B.
// final_offs(idx) = histS[idx] + bsum[idx>>10].
// ---------------------------------------------------------------------------
__global__ __launch_bounds__(256) void scan_local_kernel(
    const int* __restrict__ cnt, int* __restrict__ offs,
    int* __restrict__ bsum, int n)
{
    __shared__ int sd[256];
    int t = threadIdx.x;
    int base = blockIdx.x * 1024 + t * 4;

    int4 v = make_int4(0, 0, 0, 0);
    if (base + 3 < n) {
        v = *reinterpret_cast<const int4*>(cnt + base);
    } else {
        if (base + 0 < n) v.x = cnt[base + 0];
        if (base + 1 < n) v.y = cnt[base + 1];
        if (base + 2 < n) v.z = cnt[base + 2];
        if (base + 3 < n) v.w = cnt[base + 3];
    }
    int s = v.x + v.y + v.z + v.w;
    sd[t] = s;
    __syncthreads();
    for (int off = 1; off < 256; off <<= 1) {
        int u = (t >= off) ? sd[t - off] : 0;
        __syncthreads();
        sd[t] += u;
        __syncthreads();
    }
    int incl = sd[t];
    int excl = incl - s;
    if (t == 255) bsum[blockIdx.x] = incl;

    int p0 = excl, p1 = p0 + v.x, p2 = p1 + v.y, p3 = p2 + v.z;
    if (base + 0 < n) offs[base + 0] = p0;
    if (base + 1 < n) offs[base + 1] = p1;
    if (base + 2 < n) offs[base + 2] = p2;
    if (base + 3 < n) offs[base + 3] = p3;
}

__global__ __launch_bounds__(1024) void scan_bsum_kernel(
    int* __restrict__ bsum, int nb2)
{
    __shared__ int sd[1024];
    int t = threadIdx.x;
    int v = (t < nb2) ? bsum[t] : 0;
    sd[t] = v;
    __syncthreads();
    for (int off = 1; off < 1024; off <<= 1) {
        int u = (t >= off) ? sd[t - off] : 0;
        __syncthreads();
        sd[t] += u;
        __syncthreads();
    }
    if (t < nb2) bsum[t] = sd[t] - v;   // exclusive base per scan block
}

// ---------------------------------------------------------------------------
// Bin edges to bucket-contiguous packed array. pairs[p] = src | dstLocal<<27.
// ---------------------------------------------------------------------------
__global__ __launch_bounds__(256) void bin_kernel(
    const int* __restrict__ src, const int* __restrict__ dst,
    const int* __restrict__ histS, const int* __restrict__ bsum,
    uint* __restrict__ pairs, int n_edges, int B_, int nb)
{
    __shared__ int cur[NBMAX];
    int blk = blockIdx.x;
    for (int j = threadIdx.x; j < nb; j += 256) {
        int idx = j * B_ + blk;
        cur[j] = histS[idx] + bsum[idx >> 10];
    }
    __syncthreads();
    int base = blk * CHUNK;
#pragma unroll 4
    for (int i = 0; i < CHUNK / 256; ++i) {
        int e = base + i * 256 + threadIdx.x;
        if (e < n_edges) {
            int d = dst[e];
            int j = d >> BSH;
            int p = atomicAdd(&cur[j], 1);
            pairs[p] = (uint)src[e] | ((uint)(d & (BNODES - 1)) << 27);
        }
    }
}

// ---------------------------------------------------------------------------
// Fused aggregate + MFMA GEMM. Block = 64 nodes = 2 adjacent buckets.
// 512 threads = 8 waves: gather phase has 8 nodes/wave (x2 waves/CU vs R7)
// with 8-deep independent load unroll; GEMM phase uses 2 waves per 16-row
// group, each covering half the output tiles.
// ---------------------------------------------------------------------------
__global__ __launch_bounds__(512) void agg_gemm_kernel(
    const ushort* __restrict__ xbf, const uint* __restrict__ pairs,
    const int* __restrict__ histS, const int* __restrict__ bsum,
    const ushort* __restrict__ w1, const ushort* __restrict__ w2,
    const float* __restrict__ bias, float* __restrict__ out,
    int n_nodes, int n_edges, int B_, int nb, int flat)
{
    __shared__ uint sorted[TILE];           // 8 KB
    __shared__ uint abuf[64 * ASTRIDE];     // 17.4 KB
    __shared__ int hcnt[64];
    __shared__ int hoff[65];
    __shared__ int hcur[64];

    int blk  = blockIdx.x;
    int node0 = blk * 64;
    int b0   = blk * 2;
    int wave = threadIdx.x >> 6;
    int lane = threadIdx.x & 63;

    auto loadOffs = [&](int idx) -> int {
        if (idx >= flat) return n_edges;
        return histS[idx] + bsum[idx >> 10];
    };

    int e0  = loadOffs(b0 * B_);
    int mid = loadOffs((b0 + 1) * B_);
    int e1  = loadOffs((b0 + 2) * B_);

    const uint* xv = reinterpret_cast<const uint*>(xbf);
    float2 acc[8];
#pragma unroll
    for (int i = 0; i < 8; ++i) acc[i] = make_float2(0.f, 0.f);

    for (int t0 = e0; t0 < e1; t0 += TILE) {
        int cnt = e1 - t0; if (cnt > TILE) cnt = TILE;

        if (threadIdx.x < 64) hcnt[threadIdx.x] = 0;
        __syncthreads();

        for (int i = threadIdx.x; i < cnt; i += 512) {
            uint pk = pairs[t0 + i];
            int nl = ((t0 + i) >= mid ? BNODES : 0) + (int)(pk >> 27);
            atomicAdd(&hcnt[nl], 1);
        }
        __syncthreads();

        if (threadIdx.x < 64) {
            int v = hcnt[lane];
#pragma unroll
            for (int off = 1; off < 64; off <<= 1) {
                int u = __shfl_up(v, off);
                if (lane >= off) v += u;
            }
            hoff[lane + 1] = v;
            hcur[lane] = v - hcnt[lane];
            if (lane == 0) hoff[0] = 0;
        }
        __syncthreads();

        for (int i = threadIdx.x; i < cnt; i += 512) {
            uint pk = pairs[t0 + i];
            int nl = ((t0 + i) >= mid ? BNODES : 0) + (int)(pk >> 27);
            int p = atomicAdd(&hcur[nl], 1);
            sorted[p] = pk & 0x07ffffffu;
        }
        __syncthreads();

        // wave owns nodes wave*8 .. wave*8+7; 8-deep independent gathers
#pragma unroll
        for (int i = 0; i < 8; ++i) {
            int nl = wave * 8 + i;
            int j0 = hoff[nl], j1 = hoff[nl + 1];
            float2 a = acc[i];
            int j = j0;
            for (; j + 7 < j1; j += 8) {
                uint u0 = xv[(size_t)sorted[j + 0] * 64 + lane];
                uint u1 = xv[(size_t)sorted[j + 1] * 64 + lane];
                uint u2 = xv[(size_t)sorted[j + 2] * 64 + lane];
                uint u3 = xv[(size_t)sorted[j + 3] * 64 + lane];
                uint u4 = xv[(size_t)sorted[j + 4] * 64 + lane];
                uint u5 = xv[(size_t)sorted[j + 5] * 64 + lane];
                uint u6 = xv[(size_t)sorted[j + 6] * 64 + lane];
                uint u7 = xv[(size_t)sorted[j + 7] * 64 + lane];
                a.x += __uint_as_float(u0 << 16) + __uint_as_float(u1 << 16)
                     + __uint_as_float(u2 << 16) + __uint_as_float(u3 << 16)
                     + __uint_as_float(u4 << 16) + __uint_as_float(u5 << 16)
                     + __uint_as_float(u6 << 16) + __uint_as_float(u7 << 16);
                a.y += __uint_as_float(u0 & 0xffff0000u) + __uint_as_float(u1 & 0xffff0000u)
                     + __uint_as_float(u2 & 0xffff0000u) + __uint_as_float(u3 & 0xffff0000u)
                     + __uint_as_float(u4 & 0xffff0000u) + __uint_as_float(u5 & 0xffff0000u)
                     + __uint_as_float(u6 & 0xffff0000u) + __uint_as_float(u7 & 0xffff0000u);
            }
            for (; j + 3 < j1; j += 4) {
                uint u0 = xv[(size_t)sorted[j + 0] * 64 + lane];
                uint u1 = xv[(size_t)sorted[j + 1] * 64 + lane];
                uint u2 = xv[(size_t)sorted[j + 2] * 64 + lane];
                uint u3 = xv[(size_t)sorted[j + 3] * 64 + lane];
                a.x += __uint_as_float(u0 << 16) + __uint_as_float(u1 << 16)
                     + __uint_as_float(u2 << 16) + __uint_as_float(u3 << 16);
                a.y += __uint_as_float(u0 & 0xffff0000u) + __uint_as_float(u1 & 0xffff0000u)
                     + __uint_as_float(u2 & 0xffff0000u) + __uint_as_float(u3 & 0xffff0000u);
            }
            for (; j < j1; ++j) {
                uint u = xv[(size_t)sorted[j] * 64 + lane];
                a.x += __uint_as_float(u << 16);
                a.y += __uint_as_float(u & 0xffff0000u);
            }
            acc[i] = a;
        }
        __syncthreads();   // protect sorted/hist before next tile
    }

    // stage aggregated rows as bf16 into LDS (row stride 68 uints)
#pragma unroll
    for (int i = 0; i < 8; ++i) {
        int nl = wave * 8 + i;
        abuf[nl * ASTRIDE + lane] =
            (uint)f2bf(acc[i].x) | ((uint)f2bf(acc[i].y) << 16);
    }
    __syncthreads();

    // ---- MFMA phase: 2 waves per 16-row group; each does 4 of 8 o-tiles ----
    int quad = lane >> 4;
    int m    = lane & 15;
    int rg   = wave >> 1;          // row group 0..3
    int half = wave & 1;           // which 4 o-tiles
    int rowL = rg * 16 + m;
    int rowG = node0 + rowL;
    int rowC = (rowG < n_nodes) ? rowG : (n_nodes - 1);   // clamp loads

    short8 xa[4], aa[4];
#pragma unroll
    for (int ks = 0; ks < 4; ++ks) {
        xa[ks] = *reinterpret_cast<const short8*>(xbf + (size_t)rowC * DF + ks * 32 + quad * 8);
        aa[ks] = *reinterpret_cast<const short8*>(&abuf[rowL * ASTRIDE + ks * 16 + quad * 4]);
    }

    int nbase = node0 + rg * 16;
#pragma unroll
    for (int oi = 0; oi < 4; ++oi) {
        int ot = half * 4 + oi;
        int o = ot * 16 + m;
        floatx4 c = {0.f, 0.f, 0.f, 0.f};
#pragma unroll
        for (int ks = 0; ks < 4; ++ks) {
            short8 bf1 = *reinterpret_cast<const short8*>(w1 + (size_t)o * DF + ks * 32 + quad * 8);
            short8 bf2 = *reinterpret_cast<const short8*>(w2 + (size_t)o * DF + ks * 32 + quad * 8);
            c = __builtin_amdgcn_mfma_f32_16x16x32_bf16(xa[ks], bf1, c, 0, 0, 0);
            c = __builtin_amdgcn_mfma_f32_16x16x32_bf16(aa[ks], bf2, c, 0, 0, 0);
        }
        float bv = bias[o];
#pragma unroll
        for (int r = 0; r < 4; ++r) {
            int row = nbase + quad * 4 + r;
            if (row < n_nodes) out[(size_t)row * DF + o] = c[r] + bv;
        }
    }
}

extern "C" void kernel_launch(void* const* d_in, const int* in_sizes, int n_in,
                              void* d_out, int out_size, void* d_ws, size_t ws_size,
                              hipStream_t stream) {
    const float* x  = (const float*)d_in[0];
    const float* W1 = (const float*)d_in[1];
    const float* b1 = (const float*)d_in[2];
    const float* W2 = (const float*)d_in[3];
    const float* b2 = (const float*)d_in[4];
    const int* esrc = (const int*)d_in[5];
    const int* edst = (const int*)d_in[6];
    float* out = (float*)d_out;

    int n_nodes = in_sizes[0] / DF;
    int n_edges = in_sizes[5];

    int nb = (n_nodes + BNODES - 1) >> BSH;       // buckets (1563)
    int B_ = (n_edges + CHUNK - 1) / CHUNK;       // edge chunks (98)
    int flat = nb * B_;                           // hist matrix size (~153k)

    char* ws = (char*)d_ws;
    ushort* xbf   = (ushort*)ws;                 ws += (size_t)n_nodes * DF * 2;
    ushort* w1bf  = (ushort*)ws;                 ws += (size_t)DF * DF * 2;
    ushort* w2bf  = (ushort*)ws;                 ws += (size_t)DF * DF * 2;
    float*  bias  = (float*)ws;                  ws += (size_t)DF * 4;
    int*    histG = (int*)ws;                    ws += (size_t)flat * 4;
    int*    histS = (int*)ws;                    ws += (size_t)(flat + 1) * 4;
    int*    bsum  = (int*)ws;                    ws += 1024 * 4;
    uint*   pairs = (uint*)ws;

    int n4 = n_nodes * DF / 4;
    int prep_blocks = B_ + 64 + (n4 + 255) / 256;
    prep_kernel<<<prep_blocks, 256, 0, stream>>>(
        x, xbf, n4, W1, W2, b1, b2, w1bf, w2bf, bias,
        edst, histG, n_edges, B_, nb);

    int nb2 = (flat + 1023) / 1024;
    scan_local_kernel<<<nb2, 256, 0, stream>>>(histG, histS, bsum, flat);
    scan_bsum_kernel<<<1, 1024, 0, stream>>>(bsum, nb2);

    bin_kernel<<<B_, 256, 0, stream>>>(esrc, edst, histS, bsum, pairs, n_edges, B_, nb);

    agg_gemm_kernel<<<(n_nodes + 63) / 64, 512, 0, stream>>>(
        xbf, pairs, histS, bsum, w1bf, w2bf, bias, out,
        n_nodes, n_edges, B_, nb, flat);
}